// Round 1
// baseline (1431.949 us; speedup 1.0000x reference)
//
#include <hip/hip_runtime.h>
#include <stdint.h>

// GPUHausdorffLoss: B=64, H=W=512, SAMPLE_POINTS=1000, THRESH=0.1, MAX_RATIO=0.1
//
// Pipeline:
//  select_kernel (128 blocks, one per image-side):
//    - valid = sqrt(gx^2+gy^2+1e-8) > 0.1 of sigmoid(pred) or target (Sobel, zero pad)
//    - exact JAX threefry2x32 (partitionable derivation) noise per pixel
//    - exact top-1000-by-score selection (score = 2.0f + noise, ties -> lowest index)
//      via 2-level radix select (histograms + suffix scans in LDS)
//    - writes packed (row<<16|col) points + count into d_ws
//  haus_kernel (64 blocks): both directed Hausdorff maxima, clip, mean via atomicAdd.

#define HH 512
#define WW 512
#define NPIX (HH * WW)
#define NSEL 1000
#define BLK 1024

__device__ __forceinline__ uint32_t rotl32(uint32_t x, int r) {
  return (x << r) | (x >> (32 - r));
}

// JAX threefry2x32 (jax/_src/prng.py): 20 rounds, key schedule every 4.
__device__ __forceinline__ void tf2x32(uint32_t k0, uint32_t k1,
                                       uint32_t c0, uint32_t c1,
                                       uint32_t& o0, uint32_t& o1) {
  uint32_t ks2 = k0 ^ k1 ^ 0x1BD11BDAu;
  uint32_t x0 = c0 + k0, x1 = c1 + k1;
#define TF_R(r) { x0 += x1; x1 = rotl32(x1, (r)); x1 ^= x0; }
  TF_R(13) TF_R(15) TF_R(26) TF_R(6)
  x0 += k1;  x1 += ks2 + 1u;
  TF_R(17) TF_R(29) TF_R(16) TF_R(24)
  x0 += ks2; x1 += k0 + 2u;
  TF_R(13) TF_R(15) TF_R(26) TF_R(6)
  x0 += k0;  x1 += k1 + 3u;
  TF_R(17) TF_R(29) TF_R(16) TF_R(24)
  x0 += k1;  x1 += ks2 + 4u;
  TF_R(13) TF_R(15) TF_R(26) TF_R(6)
  x0 += ks2; x1 += k0 + 5u;
#undef TF_R
  o0 = x0; o1 = x1;
}

// Rank value m: exact float bits of (2.0f + uniform) minus bits of 2.0f.
// uniform = bitcast(bits>>9 | 0x3f800000) - 1.0 (exact); the +2.0 rounds to a
// 22-bit grid exactly as XLA does, so ties match top_k's tie structure.
__device__ __forceinline__ uint32_t pixel_m(uint32_t k0, uint32_t k1, int p) {
  uint32_t b1, b2;
  tf2x32(k0, k1, 0u, (uint32_t)p, b1, b2);
  uint32_t bits = b1 ^ b2;  // partitionable threefry: bits1 ^ bits2 for 32-bit draw
  float noise = __uint_as_float((bits >> 9) | 0x3F800000u) - 1.0f;
  float score = 2.0f + noise;
  return __float_as_uint(score) - 0x40000000u;  // 0 .. 0x400000 inclusive
}

__device__ __forceinline__ float sigf(float x) { return 1.0f / (1.0f + __expf(-x)); }

__device__ __forceinline__ bool pix_valid(const float* __restrict__ img, int p, bool isPred) {
  int r = p >> 9, c = p & 511;
  bool up = r > 0, dn = r < HH - 1, lf = c > 0, rt = c < WW - 1;
  const float* ctr = img + p;
  float tl = 0.f, tcv = 0.f, trv = 0.f, ml = 0.f, mr = 0.f, bl = 0.f, bcv = 0.f, brv = 0.f;
  if (isPred) {  // zero-pad applies AFTER sigmoid (conv pads the prob map with 0)
    if (up) { tcv = sigf(ctr[-WW]); if (lf) tl = sigf(ctr[-WW - 1]); if (rt) trv = sigf(ctr[-WW + 1]); }
    if (lf) ml = sigf(ctr[-1]);
    if (rt) mr = sigf(ctr[1]);
    if (dn) { bcv = sigf(ctr[WW]); if (lf) bl = sigf(ctr[WW - 1]); if (rt) brv = sigf(ctr[WW + 1]); }
  } else {
    if (up) { tcv = ctr[-WW]; if (lf) tl = ctr[-WW - 1]; if (rt) trv = ctr[-WW + 1]; }
    if (lf) ml = ctr[-1];
    if (rt) mr = ctr[1];
    if (dn) { bcv = ctr[WW]; if (lf) bl = ctr[WW - 1]; if (rt) brv = ctr[WW + 1]; }
  }
  // Sobel (sign irrelevant: only squares used)
  float gx = (trv - tl) + 2.0f * (mr - ml) + (brv - bl);
  float gy = (bl - tl) + 2.0f * (bcv - tcv) + (brv - trv);
  float bm = sqrtf(gx * gx + gy * gy + 1e-8f);
  return bm > 0.1f;
}

// In-place suffix-sum transform of hist[0..N) (N = k*1024), then find the
// largest index T with suffix[T] >= need; writes T and suffix[T+1] (count
// strictly above T) to the shared outputs. Requires blockDim.x == 1024.
__device__ void suffix_and_find(int* hist, int N, int* aux, int need,
                                int* outT, int* outAbove) {
  const int tid = threadIdx.x;
  const int k = N >> 10;
  const int base = tid * k;
  int s = 0;
  for (int i = k - 1; i >= 0; --i) { s += hist[base + i]; hist[base + i] = s; }
  aux[tid] = s;
  __syncthreads();
  for (int ofs = 1; ofs < 1024; ofs <<= 1) {  // Hillis-Steele inclusive suffix
    int v = (tid + ofs < 1024) ? aux[tid + ofs] : 0;
    __syncthreads();
    aux[tid] += v;
    __syncthreads();
  }
  int add = (tid < 1023) ? aux[tid + 1] : 0;
  for (int i = 0; i < k; ++i) hist[base + i] += add;
  __syncthreads();
  for (int i = 0; i < k; ++i) {
    int idx = base + i;
    int sfx = hist[idx];
    int nxt = (idx + 1 < N) ? hist[idx + 1] : 0;
    if (sfx >= need && nxt < need) { *outT = idx; *outAbove = nxt; }
  }
  __syncthreads();
}

__global__ __launch_bounds__(BLK) void select_kernel(
    const float* __restrict__ pred, const float* __restrict__ tgt,
    uint32_t* __restrict__ pts, int* __restrict__ counts) {
  const int b = blockIdx.x;           // 0..63 pred images, 64..127 target images
  const int tid = threadIdx.x;
  const bool isPred = b < 64;
  const float* img = isPred ? pred + (size_t)b * NPIX
                            : tgt + (size_t)(b - 64) * NPIX;

  __shared__ uint32_t bitmap[NPIX / 32];  // 32 KiB valid bitmap
  __shared__ int hist[4096 + 64];         // level-1 uses 1025 bins (pad->2048), level-2 4096
  __shared__ int aux[1024];
  __shared__ uint32_t tieIdx[1024];
  __shared__ int sh_T1, sh_T2, sh_cA, sh_cB, sh_cv, sh_tie_n, sh_sel_n;

  // keys[i] = threefry(base=(0,1), counter=(0,i))  (partitionable split)
  uint32_t k0, k1;
  tf2x32(0u, 1u, 0u, (uint32_t)b, k0, k1);

  for (int i = tid; i < NPIX / 32; i += BLK) bitmap[i] = 0u;
  for (int i = tid; i < 4096 + 64; i += BLK) hist[i] = 0;
  if (tid == 0) { sh_cv = 0; sh_tie_n = 0; sh_sel_n = 0; }
  __syncthreads();

  // ---- pass 1: validity (Sobel) + level-1 histogram (m >> 12) + bitmap ----
  int myValid = 0;
  for (int p = tid; p < NPIX; p += BLK) {
    if (pix_valid(img, p, isPred)) {
      atomicOr(&bitmap[p >> 5], 1u << (p & 31));
      uint32_t m = pixel_m(k0, k1, p);
      atomicAdd(&hist[m >> 12], 1);
      myValid++;
    }
  }
  atomicAdd(&sh_cv, myValid);
  __syncthreads();
  const int cv = sh_cv;
  const bool selAll = (cv <= NSEL);
  int vstar = 0, r2 = 0;

  if (!selAll) {
    suffix_and_find(hist, 2048, aux, NSEL, &sh_T1, &sh_cA);
    const int T1 = sh_T1;
    const int r1 = NSEL - sh_cA;  // still needed from bucket T1 (>=1)
    __syncthreads();
    for (int i = tid; i < 4096 + 64; i += BLK) hist[i] = 0;
    __syncthreads();
    // ---- pass 2: level-2 histogram (m & 4095) within bucket T1 ----
    for (int p = tid; p < NPIX; p += BLK) {
      if ((bitmap[p >> 5] >> (p & 31)) & 1u) {
        uint32_t m = pixel_m(k0, k1, p);
        if ((int)(m >> 12) == T1) atomicAdd(&hist[m & 4095], 1);
      }
    }
    __syncthreads();
    suffix_and_find(hist, 4096, aux, r1, &sh_T2, &sh_cB);
    vstar = (T1 << 12) | sh_T2;   // exact 22-bit threshold rank value
    r2 = r1 - sh_cB;              // how many exact-ties to take (smallest index)
  }
  __syncthreads();

  // ---- pass 3: emit points with m > vstar; collect exact ties ----
  for (int p = tid; p < NPIX; p += BLK) {
    if ((bitmap[p >> 5] >> (p & 31)) & 1u) {
      bool take = selAll, tie = false;
      if (!selAll) {
        uint32_t m = pixel_m(k0, k1, p);
        take = ((int)m > vstar);
        tie = ((int)m == vstar);
      }
      if (take) {
        int pos = atomicAdd(&sh_sel_n, 1);
        pts[b * NSEL + pos] = ((uint32_t)(p >> 9) << 16) | (uint32_t)(p & 511);
      } else if (tie) {
        int tp = atomicAdd(&sh_tie_n, 1);
        if (tp < 1024) tieIdx[tp] = (uint32_t)p;
      }
    }
  }
  __syncthreads();

  if (!selAll) {  // top_k breaks ties by lowest flat index
    int tn = sh_tie_n < 1024 ? sh_tie_n : 1024;
    for (int e = tid; e < tn; e += BLK) {
      uint32_t my = tieIdx[e];
      int rank = 0;
      for (int j = 0; j < tn; ++j) rank += (tieIdx[j] < my) ? 1 : 0;
      if (rank < r2) {
        int pos = atomicAdd(&sh_sel_n, 1);
        pts[b * NSEL + pos] = ((my >> 9) << 16) | (my & 511u);
      }
    }
  }
  __syncthreads();

  if (tid == 0) {
    int n = sh_sel_n;
    if (n == 0) { pts[b * NSEL] = (256u << 16) | 256u; n = 1; }  // center fallback
    counts[b] = n;
  }
}

__global__ __launch_bounds__(BLK) void haus_kernel(
    const uint32_t* __restrict__ pts, const int* __restrict__ counts,
    float* __restrict__ out) {
  const int img = blockIdx.x;  // 0..63
  const int tid = threadIdx.x;
  const int np = counts[img], nt = counts[64 + img];
  const uint32_t* P = pts + img * NSEL;
  const uint32_t* T = pts + (64 + img) * NSEL;

  __shared__ float bx[NSEL], by[NSEL];
  __shared__ float red[BLK];
  __shared__ float sh_maxA;

  // direction A: max over pred points of min d^2 to target points
  for (int i = tid; i < nt; i += BLK) {
    uint32_t v = T[i]; bx[i] = (float)(v >> 16); by[i] = (float)(v & 0xFFFFu);
  }
  __syncthreads();
  float best = -1e30f;
  for (int p = tid; p < np; p += BLK) {
    uint32_t v = P[p];
    float pr = (float)(v >> 16), pc = (float)(v & 0xFFFFu);
    float mn = 3.4e38f;
    for (int t = 0; t < nt; ++t) {
      float dr = pr - bx[t], dc = pc - by[t];
      mn = fminf(mn, dr * dr + dc * dc);
    }
    best = fmaxf(best, mn);
  }
  red[tid] = best;
  __syncthreads();
  for (int s = 512; s > 0; s >>= 1) {
    if (tid < s) red[tid] = fmaxf(red[tid], red[tid + s]);
    __syncthreads();
  }
  if (tid == 0) sh_maxA = red[0];
  __syncthreads();
  const float maxA = sh_maxA;

  // direction B: max over target points of min d^2 to pred points
  for (int i = tid; i < np; i += BLK) {
    uint32_t v = P[i]; bx[i] = (float)(v >> 16); by[i] = (float)(v & 0xFFFFu);
  }
  __syncthreads();
  best = -1e30f;
  for (int t = tid; t < nt; t += BLK) {
    uint32_t v = T[t];
    float tr = (float)(v >> 16), tc = (float)(v & 0xFFFFu);
    float mn = 3.4e38f;
    for (int p = 0; p < np; ++p) {
      float dr = tr - bx[p], dc = tc - by[p];
      mn = fminf(mn, dr * dr + dc * dc);
    }
    best = fmaxf(best, mn);
  }
  red[tid] = best;
  __syncthreads();
  for (int s = 512; s > 0; s >>= 1) {
    if (tid < s) red[tid] = fmaxf(red[tid], red[tid + s]);
    __syncthreads();
  }
  if (tid == 0) {
    float a = sqrtf(fmaxf(maxA, 0.0f));
    float bb = sqrtf(fmaxf(red[0], 0.0f));
    float hd = fmaxf(a, bb) / sqrtf(524288.0f);   // diag = sqrt(512^2+512^2)
    hd = fminf(fmaxf(hd, 0.0f), 0.1f);
    atomicAdd(out, hd * 0.015625f);               // mean over 64 (exact scale)
  }
}

extern "C" void kernel_launch(void* const* d_in, const int* in_sizes, int n_in,
                              void* d_out, int out_size, void* d_ws, size_t ws_size,
                              hipStream_t stream) {
  const float* pred = (const float*)d_in[0];
  const float* tgt = (const float*)d_in[1];
  float* out = (float*)d_out;

  int* counts = (int*)d_ws;                           // 128 ints
  uint32_t* pts = (uint32_t*)((char*)d_ws + 512);     // 128 * 1000 packed points

  hipMemsetAsync(d_out, 0, (size_t)out_size * sizeof(float), stream);
  select_kernel<<<128, BLK, 0, stream>>>(pred, tgt, pts, counts);
  haus_kernel<<<64, BLK, 0, stream>>>(pts, counts, out);
}

// Round 2
// 661.148 us; speedup vs baseline: 2.1659x; 2.1659x over previous
//
#include <hip/hip_runtime.h>
#include <stdint.h>

// GPUHausdorffLoss — pipeline:
//  K1 sobel_hist  (2048 blk x 256): Sobel valid (register-rolling sigmoid window),
//                 threefry m once/pixel, per-image 4096-bin global hist, valid bits
//                 in thread-owned bitmap words (no atomics for bitmap).
//  K2 thresh      (128 blk): suffix-scan hist -> threshold bin T, countAbove, r.
//  K3 collect     (2048 blk): re-threefry valid px; emit bin>T points + bin==T cands.
//  K4 resolve     (128 blk): exact (m desc, idx asc) tie-resolution among cands.
//  K5 haus        (256 blk): per (img, dir, half) partial max of min d^2, atomicMax.
//  K6 finalize    (1 blk): hd = clip(sqrt(maxd2)/diag, 0, 0.1); mean -> out.

#define HH 512
#define WW 512
#define NPIX (HH * WW)
#define NSEL 1000
#define NBIN 4096
#define CANDCAP 4096
#define SLICES 16          // rows per slice = 32
#define ROWS_PER 32

__device__ __forceinline__ uint32_t rotl32(uint32_t x, int r) {
  return (x << r) | (x >> (32 - r));
}

// JAX threefry2x32: 20 rounds, key schedule every 4.
__device__ __forceinline__ void tf2x32(uint32_t k0, uint32_t k1,
                                       uint32_t c0, uint32_t c1,
                                       uint32_t& o0, uint32_t& o1) {
  uint32_t ks2 = k0 ^ k1 ^ 0x1BD11BDAu;
  uint32_t x0 = c0 + k0, x1 = c1 + k1;
#define TF_R(r) { x0 += x1; x1 = rotl32(x1, (r)); x1 ^= x0; }
  TF_R(13) TF_R(15) TF_R(26) TF_R(6)
  x0 += k1;  x1 += ks2 + 1u;
  TF_R(17) TF_R(29) TF_R(16) TF_R(24)
  x0 += ks2; x1 += k0 + 2u;
  TF_R(13) TF_R(15) TF_R(26) TF_R(6)
  x0 += k0;  x1 += k1 + 3u;
  TF_R(17) TF_R(29) TF_R(16) TF_R(24)
  x0 += k1;  x1 += ks2 + 4u;
  TF_R(13) TF_R(15) TF_R(26) TF_R(6)
  x0 += ks2; x1 += k0 + 5u;
#undef TF_R
  o0 = x0; o1 = x1;
}

// Exact rank value of score = 2.0f + uniform(bits): bits of score minus bits of 2.0f.
__device__ __forceinline__ uint32_t pixel_m(uint32_t k0, uint32_t k1, int p) {
  uint32_t b1, b2;
  tf2x32(k0, k1, 0u, (uint32_t)p, b1, b2);
  uint32_t bits = b1 ^ b2;
  float noise = __uint_as_float((bits >> 9) | 0x3F800000u) - 1.0f;
  float score = 2.0f + noise;
  return __float_as_uint(score) - 0x40000000u;  // 0 .. 0x400000 inclusive
}

__device__ __forceinline__ float sigf(float x) { return 1.0f / (1.0f + __expf(-x)); }

__device__ __forceinline__ float ldval(const float* __restrict__ img, int r, int c, bool isPred) {
  if (r < 0 || r > HH - 1 || c < 0 || c > WW - 1) return 0.0f;  // conv zero-pad (post-sigmoid)
  float v = img[r * WW + c];
  return isPred ? sigf(v) : v;
}

// ---------------- K1 ----------------
__global__ __launch_bounds__(256) void sobel_hist(
    const float* __restrict__ pred, const float* __restrict__ tgt,
    int* __restrict__ g_hist, int* __restrict__ g_cv, uint32_t* __restrict__ g_bmp) {
  const int bid = blockIdx.x;
  const int b = bid >> 4;            // image-side 0..127
  const int s = bid & 15;            // slice
  const int r0 = s * ROWS_PER;
  const int t = threadIdx.x;
  const bool isPred = b < 64;
  const float* img = isPred ? pred + (size_t)b * NPIX : tgt + (size_t)(b - 64) * NPIX;

  __shared__ int hist[NBIN];
  __shared__ int s_cv;
  for (int i = t; i < NBIN; i += 256) hist[i] = 0;
  if (t == 0) s_cv = 0;
  __syncthreads();

  uint32_t k0, k1;
  tf2x32(0u, 1u, 0u, (uint32_t)b, k0, k1);

  const int c0 = 2 * t;  // this thread's two columns
  // rolling 3x4 sigmoid/value window: rows r-1 (a), r (bv), r+1 (d); cols c0-1..c0+2
  float a0 = ldval(img, r0 - 1, c0 - 1, isPred), a1 = ldval(img, r0 - 1, c0, isPred),
        a2 = ldval(img, r0 - 1, c0 + 1, isPred), a3 = ldval(img, r0 - 1, c0 + 2, isPred);
  float b0 = ldval(img, r0, c0 - 1, isPred), b1 = ldval(img, r0, c0, isPred),
        b2 = ldval(img, r0, c0 + 1, isPred), b3 = ldval(img, r0, c0 + 2, isPred);
  float d0 = ldval(img, r0 + 1, c0 - 1, isPred), d1 = ldval(img, r0 + 1, c0, isPred),
        d2 = ldval(img, r0 + 1, c0 + 1, isPred), d3 = ldval(img, r0 + 1, c0 + 2, isPred);

  uint32_t w0 = 0, w1 = 0;
  for (int rr = 0; rr < ROWS_PER; ++rr) {
    const int r = r0 + rr;
    // pixel (r, c0)
    {
      float gx = (a2 - a0) + 2.0f * (b2 - b0) + (d2 - d0);
      float gy = (d0 - a0) + 2.0f * (d1 - a1) + (d2 - a2);
      float bm = sqrtf(gx * gx + gy * gy + 1e-8f);
      if (bm > 0.1f) {
        w0 |= (1u << rr);
        uint32_t m = pixel_m(k0, k1, r * WW + c0);
        uint32_t bin = m >> 10; if (bin > NBIN - 1) bin = NBIN - 1;
        atomicAdd(&hist[bin], 1);
      }
    }
    // pixel (r, c0+1)
    {
      float gx = (a3 - a1) + 2.0f * (b3 - b1) + (d3 - d1);
      float gy = (d1 - a1) + 2.0f * (d2 - a2) + (d3 - a3);
      float bm = sqrtf(gx * gx + gy * gy + 1e-8f);
      if (bm > 0.1f) {
        w1 |= (1u << rr);
        uint32_t m = pixel_m(k0, k1, r * WW + c0 + 1);
        uint32_t bin = m >> 10; if (bin > NBIN - 1) bin = NBIN - 1;
        atomicAdd(&hist[bin], 1);
      }
    }
    if (rr < ROWS_PER - 1) {
      a0 = b0; a1 = b1; a2 = b2; a3 = b3;
      b0 = d0; b1 = d1; b2 = d2; b3 = d3;
      d0 = ldval(img, r + 2, c0 - 1, isPred);
      d1 = ldval(img, r + 2, c0, isPred);
      d2 = ldval(img, r + 2, c0 + 1, isPred);
      d3 = ldval(img, r + 2, c0 + 2, isPred);
    }
  }
  // thread-owned bitmap words: layout [block][2t], [block][2t+1]
  g_bmp[(size_t)bid * 512 + 2 * t] = w0;
  g_bmp[(size_t)bid * 512 + 2 * t + 1] = w1;
  atomicAdd(&s_cv, __popc(w0) + __popc(w1));
  __syncthreads();
  if (t == 0) atomicAdd(&g_cv[b], s_cv);
  for (int i = t; i < NBIN; i += 256) {
    int h = hist[i];
    if (h) atomicAdd(&g_hist[b * NBIN + i], h);
  }
}

// ---------------- K2 ----------------
__global__ __launch_bounds__(256) void thresh_kernel(
    const int* __restrict__ g_hist, const int* __restrict__ g_cv,
    int* __restrict__ g_params) {
  const int img = blockIdx.x;
  const int t = threadIdx.x;
  __shared__ int h[NBIN];
  __shared__ int aux[256];
  const int cv = g_cv[img];
  int* params = g_params + img * 4;
  if (cv <= NSEL) {
    if (t == 0) { params[0] = 1; params[1] = 0; params[2] = 0; params[3] = 0; }
    return;
  }
  for (int i = t; i < NBIN; i += 256) h[i] = g_hist[img * NBIN + i];
  __syncthreads();
  const int base = t * 16;
  int s = 0;
  for (int i = 15; i >= 0; --i) { s += h[base + i]; h[base + i] = s; }
  aux[t] = s;
  __syncthreads();
  for (int o = 1; o < 256; o <<= 1) {
    int v = (t + o < 256) ? aux[t + o] : 0;
    __syncthreads();
    aux[t] += v;
    __syncthreads();
  }
  int add = (t < 255) ? aux[t + 1] : 0;
  for (int i = 0; i < 16; ++i) h[base + i] += add;
  __syncthreads();
  for (int i = 0; i < 16; ++i) {
    int idx = base + i;
    int sfx = h[idx];
    int nxt = (idx + 1 < NBIN) ? h[idx + 1] : 0;
    if (sfx >= NSEL && nxt < NSEL) {
      params[0] = 0;          // normal
      params[1] = idx;        // threshold bin T
      params[2] = NSEL - nxt; // r: how many needed from bin T
      params[3] = nxt;        // count above
    }
  }
}

// ---------------- K3 ----------------
__global__ __launch_bounds__(256) void collect_kernel(
    const uint32_t* __restrict__ g_bmp, const int* __restrict__ g_params,
    int* __restrict__ g_counts, uint32_t* __restrict__ g_pts,
    int* __restrict__ g_candc, unsigned long long* __restrict__ g_cand) {
  const int bid = blockIdx.x;
  const int b = bid >> 4;
  const int s = bid & 15;
  const int r0 = s * ROWS_PER;
  const int t = threadIdx.x;
  const int flag = g_params[b * 4 + 0];
  const int T = g_params[b * 4 + 1];
  uint32_t k0, k1;
  tf2x32(0u, 1u, 0u, (uint32_t)b, k0, k1);
  const int c0 = 2 * t;
  uint32_t w0 = g_bmp[(size_t)bid * 512 + 2 * t];
  uint32_t w1 = g_bmp[(size_t)bid * 512 + 2 * t + 1];
  for (int rr = 0; rr < ROWS_PER; ++rr) {
    const int r = r0 + rr;
    for (int k = 0; k < 2; ++k) {
      uint32_t w = k ? w1 : w0;
      if ((w >> rr) & 1u) {
        const int c = c0 + k;
        const int p = r * WW + c;
        if (flag) {
          int pos = atomicAdd(&g_counts[b], 1);
          g_pts[b * NSEL + pos] = ((uint32_t)r << 16) | (uint32_t)c;
        } else {
          uint32_t m = pixel_m(k0, k1, p);
          uint32_t bin = m >> 10; if (bin > NBIN - 1) bin = NBIN - 1;
          if ((int)bin > T) {
            int pos = atomicAdd(&g_counts[b], 1);
            g_pts[b * NSEL + pos] = ((uint32_t)r << 16) | (uint32_t)c;
          } else if ((int)bin == T) {
            int cp = atomicAdd(&g_candc[b], 1);
            if (cp < CANDCAP)
              g_cand[(size_t)b * CANDCAP + cp] = ((unsigned long long)m << 32) | (uint32_t)p;
          }
        }
      }
    }
  }
}

// ---------------- K4 ----------------
__global__ __launch_bounds__(256) void resolve_kernel(
    const int* __restrict__ g_params, const int* __restrict__ g_cv,
    int* __restrict__ g_counts, uint32_t* __restrict__ g_pts,
    const int* __restrict__ g_candc, const unsigned long long* __restrict__ g_cand) {
  const int img = blockIdx.x;
  const int t = threadIdx.x;
  const int flag = g_params[img * 4 + 0];
  if (flag) {  // selAll: counts already == cv; handle cv==0 center fallback
    if (g_cv[img] == 0 && t == 0) {
      g_pts[img * NSEL] = (256u << 16) | 256u;
      g_counts[img] = 1;
    }
    return;
  }
  const int rneed = g_params[img * 4 + 2];
  int nc = g_candc[img]; if (nc > CANDCAP) nc = CANDCAP;
  __shared__ unsigned long long sc[CANDCAP];
  for (int i = t; i < nc; i += 256) sc[i] = g_cand[(size_t)img * CANDCAP + i];
  __syncthreads();
  for (int i = t; i < nc; i += 256) {
    unsigned long long ki = sc[i];
    uint32_t mi = (uint32_t)(ki >> 32), pi = (uint32_t)ki;
    int rank = 0;
    for (int j = 0; j < nc; ++j) {
      unsigned long long kj = sc[j];
      uint32_t mj = (uint32_t)(kj >> 32), pj = (uint32_t)kj;
      rank += (mj > mi) || (mj == mi && pj < pi);
    }
    if (rank < rneed) {
      int pos = atomicAdd(&g_counts[img], 1);
      uint32_t r = pi >> 9, c = pi & 511u;
      g_pts[img * NSEL + pos] = (r << 16) | c;
    }
  }
}

// ---------------- K5 ----------------
__global__ __launch_bounds__(256) void haus_kernel(
    const uint32_t* __restrict__ g_pts, const int* __restrict__ g_counts,
    float* __restrict__ g_maxd2) {
  const int bid = blockIdx.x;
  const int img = bid >> 2;
  const int dir = (bid >> 1) & 1;
  const int half = bid & 1;
  const int t = threadIdx.x;
  const int iOwn = dir ? 64 + img : img;
  const int iOth = dir ? img : 64 + img;
  const int nOwn = g_counts[iOwn];
  const int nOth = g_counts[iOth];
  __shared__ float2 o[NSEL];
  __shared__ float red[256];
  for (int i = t; i < nOth; i += 256) {
    uint32_t v = g_pts[iOth * NSEL + i];
    o[i] = make_float2((float)(v >> 16), (float)(v & 0xFFFFu));
  }
  __syncthreads();
  float best = 0.0f;  // d^2 >= 0
  const int lo = half * 500;
  const int hi = min(nOwn, lo + 500);
  for (int i = lo + t; i < hi; i += 256) {
    uint32_t v = g_pts[iOwn * NSEL + i];
    float pr = (float)(v >> 16), pc = (float)(v & 0xFFFFu);
    float mn = 3.4e38f;
    for (int j = 0; j < nOth; ++j) {
      float dr = pr - o[j].x, dc = pc - o[j].y;
      mn = fminf(mn, dr * dr + dc * dc);
    }
    best = fmaxf(best, mn);
  }
  red[t] = best;
  __syncthreads();
  for (int st = 128; st > 0; st >>= 1) {
    if (t < st) red[t] = fmaxf(red[t], red[t + st]);
    __syncthreads();
  }
  if (t == 0) atomicMax((unsigned int*)&g_maxd2[img], __float_as_uint(red[0]));
}

// ---------------- K6 ----------------
__global__ __launch_bounds__(64) void fin_kernel(const float* __restrict__ g_maxd2,
                                                 float* __restrict__ out) {
  const int t = threadIdx.x;
  float diag = sqrtf((float)(HH * HH + WW * WW));
  float hd = sqrtf(fmaxf(g_maxd2[t], 0.0f)) / diag;
  hd = fminf(fmaxf(hd, 0.0f), 0.1f);
  float s = hd;
  for (int o = 32; o > 0; o >>= 1) s += __shfl_down(s, o);
  if (t == 0) out[0] = s * 0.015625f;
}

// ---------------- workspace layout (bytes) ----------------
#define WS_HIST   0u                                   // 128*4096*4 = 2097152
#define WS_CV     2097152u                             // 512
#define WS_COUNTS (WS_CV + 512u)                       // 512
#define WS_CANDC  (WS_COUNTS + 512u)                   // 512
#define WS_MAXD2  (WS_CANDC + 512u)                    // 256
#define WS_PARAMS (WS_MAXD2 + 256u)                    // 2048
#define WS_PTS    (WS_PARAMS + 2048u)                  // 512000
#define WS_CAND   (WS_PTS + 512000u)                   // 128*4096*8 = 4194304
#define WS_BMP    (WS_CAND + 4194304u)                 // 128*16*512*4 = 4194304

extern "C" void kernel_launch(void* const* d_in, const int* in_sizes, int n_in,
                              void* d_out, int out_size, void* d_ws, size_t ws_size,
                              hipStream_t stream) {
  const float* pred = (const float*)d_in[0];
  const float* tgt = (const float*)d_in[1];
  float* out = (float*)d_out;
  char* ws = (char*)d_ws;
  int* g_hist = (int*)(ws + WS_HIST);
  int* g_cv = (int*)(ws + WS_CV);
  int* g_counts = (int*)(ws + WS_COUNTS);
  int* g_candc = (int*)(ws + WS_CANDC);
  float* g_maxd2 = (float*)(ws + WS_MAXD2);
  int* g_params = (int*)(ws + WS_PARAMS);
  uint32_t* g_pts = (uint32_t*)(ws + WS_PTS);
  unsigned long long* g_cand = (unsigned long long*)(ws + WS_CAND);
  uint32_t* g_bmp = (uint32_t*)(ws + WS_BMP);

  // zero hist + counters (+params region, harmless)
  hipMemsetAsync(d_ws, 0, WS_PTS, stream);
  sobel_hist<<<128 * SLICES, 256, 0, stream>>>(pred, tgt, g_hist, g_cv, g_bmp);
  thresh_kernel<<<128, 256, 0, stream>>>(g_hist, g_cv, g_params);
  collect_kernel<<<128 * SLICES, 256, 0, stream>>>(g_bmp, g_params, g_counts, g_pts, g_candc, g_cand);
  resolve_kernel<<<128, 256, 0, stream>>>(g_params, g_cv, g_counts, g_pts, g_candc, g_cand);
  haus_kernel<<<256, 256, 0, stream>>>(g_pts, g_counts, g_maxd2);
  fin_kernel<<<1, 64, 0, stream>>>(g_maxd2, out);
}